// Round 9
// baseline (386.378 us; speedup 1.0000x reference)
//
#include <hip/hip_runtime.h>

// arHOCA: L=200 positions, Q=21 alphabet, H=128 hidden, B=256 batch.
// x is one-hot => all "x @ W" contractions are gather-sums over idx[b,l].
//
// DCA mask (faithful to reference): mask loop is `for i in range(Q)`, so only
// row-blocks 1..20 / col-blocks 0..19 are active; mask[d,c]=1 iff blk(c)<blk(d).
// => out_dca[b,j] = sum_{l=j/Q+1}^{20} DW[l*Q+idx[b,l], j].
//
// k_h1 is a chunked LDS-broadcast streamer: block = (l, 32-wide lp-chunk);
// each W1 byte is read from HBM exactly once (chunks are disjoint); per-lp the
// 21 candidate rows (10.5 KB) sit in LDS and are broadcast to all 256 batches.
// Partial sums (per chunk) go to ws; k_h2 sums partials + bias + lrelu.
//
// ws layout: idxT [200][256] int (204800 B)
//            | part [199][7][256][128] f32 (182583296 B)
//            | h2T [199][128][256] f32 (26083328 B)   => ~209 MB.

#define Lc   200
#define Qc   21
#define Hc   128
#define Bc   256
#define LQc  4200
#define LM1c 199
#define CH   32    // lp chunk size
#define NCH  7     // max chunks per l

// ---------------- K0: idxT[l][b] = argmax_c x[b,l,c] ----------------
__global__ __launch_bounds__(256) void k_idx(const float* __restrict__ x,
                                             int* __restrict__ idxT) {
    const int l = blockIdx.x;       // 0..199
    const int b = threadIdx.x;      // 0..255
    const float* p = x + ((size_t)b * Lc + l) * Qc;
    int id = 0;
#pragma unroll
    for (int c = 0; c < Qc; ++c) id = (p[c] > 0.5f) ? c : id;
    idxT[l * Bc + b] = id;          // coalesced store
}

// ---------------- K1: DCA gather + bias + out0 (w0+b0) ----------------
// out[b, j] = bias[j] + sum_{l = j/Q+1 .. 20} DW[l*Q+idx[b,l], j]  (+ w0+b0 for j<Q)
__global__ __launch_bounds__(256) void k_dca(const float* __restrict__ DW,
                                             const float* __restrict__ bias,
                                             const float* __restrict__ w0,
                                             const float* __restrict__ b0,
                                             const int* __restrict__ idxT,
                                             float* __restrict__ out) {
    const int b = blockIdx.x / 5, chunk = blockIdx.x % 5;
    const int j0 = chunk * 1024 + threadIdx.x * 4;
    if (j0 >= LQc) return;
    float a[4];
    const float4 bv = *(const float4*)(bias + j0);
    a[0] = bv.x; a[1] = bv.y; a[2] = bv.z; a[3] = bv.w;
    if (j0 < Qc) {
#pragma unroll
        for (int e = 0; e < 4; ++e) {
            int j = j0 + e;
            if (j < Qc) a[e] += w0[j] + b0[j];
        }
    }
    if (j0 < (Qc - 1) * Qc) {
        const int lmin = j0 / Qc + 1;
        for (int l = lmin; l < Qc; ++l) {
            const int iv = idxT[l * Bc + b];
            const float4 v = *(const float4*)(DW + (size_t)(l * Qc + iv) * LQc + j0);
            const int thr = l * Qc;  // contribute iff j < l*Q
            a[0] += (j0     < thr) ? v.x : 0.f;
            a[1] += (j0 + 1 < thr) ? v.y : 0.f;
            a[2] += (j0 + 2 < thr) ? v.z : 0.f;
            a[3] += (j0 + 3 < thr) ? v.w : 0.f;
        }
    }
    float4 o = {a[0], a[1], a[2], a[3]};
    *(float4*)(out + (size_t)b * LQc + j0) = o;
}

// ---------------- K2: chunked LDS-broadcast partial sums ----------------
// part[l][c][b][h] = sum_{lp in chunk c, lp<=l} W1[l, lp*Q+idx[b,lp], h]
// Block = (l, chunk), 512 threads (8 waves). Thread = (hq = h-quad, bg = batch
// group of 16). Per lp: the 21-row tile (10.5 KB) is staged once (async,
// reg-staged, double-buffered, ONE barrier/iter) and broadcast-read from LDS.
// Each W1 element: exactly one HBM fetch, kernel-wide.
__global__ __launch_bounds__(512, 4) void k_h1(const float* __restrict__ W1,
                                               const int* __restrict__ idxT,
                                               float* __restrict__ part) {
    const int bid = blockIdx.x;            // 0..1392
    const int l = bid / NCH, c = bid % NCH;
    const int lo = c * CH;
    if (lo > l) return;                    // invalid chunk for this l
    const int hi = (l < lo + CH - 1) ? l : lo + CH - 1;
    const int n = hi - lo + 1;             // 1..32 iterations

    const int t = threadIdx.x;
    const int hq = t & 31;                 // h-quad: h = hq*4 .. hq*4+3
    const int bg = t >> 5;                 // batch group: b = bg*16 .. bg*16+15

    __shared__ __align__(16) float tile[2][Qc * 132];  // padded rows (132 floats)
    __shared__ int idxs[CH * Bc];

    // stage all chunk idx rows (n*256 ints = n*64 int4), coalesced
    {
        const int4* isrc = (const int4*)(idxT + lo * Bc);
        int4* idst = (int4*)idxs;
        for (int i = t; i < n * 64; i += 512) idst[i] = isrc[i];
    }

    // stage tile 0 (2688 floats = 672 float4): i -> row i>>5, col (i&31)*4
    const float* Wsrc = W1 + (size_t)l * (LQc * Hc) + (size_t)lo * (Qc * Hc);
    {
        const float4* src = (const float4*)Wsrc;
        const float4 q0 = src[t];
        float4 q1;
        if (t < 160) q1 = src[512 + t];
        *(float4*)&tile[0][(t >> 5) * 132 + (t & 31) * 4] = q0;
        if (t < 160) *(float4*)&tile[0][(16 + (t >> 5)) * 132 + (t & 31) * 4] = q1;
    }
    __syncthreads();

    float4 acc[16];
#pragma unroll
    for (int j = 0; j < 16; ++j) acc[j] = (float4){0.f, 0.f, 0.f, 0.f};

    int cur = 0;
    for (int k = 0; k < n; ++k) {
        // async stage-ahead: issue global loads for tile k+1 (regs)
        float4 p0, p1;
        const bool has = (k + 1 < n);
        if (has) {
            const float4* src = (const float4*)(Wsrc + (size_t)(k + 1) * (Qc * Hc));
            p0 = src[t];
            if (t < 160) p1 = src[512 + t];
        }
        // broadcast-accumulate tile k (HBM latency of p0/p1 hides under this)
        const float* tb = &tile[cur][hq * 4];
        const int* ib = &idxs[k * Bc + bg * 16];
#pragma unroll
        for (int j = 0; j < 16; ++j) {
            const int row = ib[j];
            const float4 v = *(const float4*)(tb + row * 132);
            acc[j].x += v.x; acc[j].y += v.y; acc[j].z += v.z; acc[j].w += v.w;
        }
        // write tile k+1 into the other buffer (its readers finished before
        // the previous barrier), then ONE barrier
        if (has) {
            float* dst = tile[cur ^ 1];
            *(float4*)&dst[(t >> 5) * 132 + (t & 31) * 4] = p0;
            if (t < 160) *(float4*)&dst[(16 + (t >> 5)) * 132 + (t & 31) * 4] = p1;
        }
        __syncthreads();
        cur ^= 1;
    }

    // store partials: part[(l*7+c)][b][h], 512B-contiguous per half-wave
    float* pb = part + ((size_t)(l * NCH + c) * Bc + bg * 16) * Hc + hq * 4;
#pragma unroll
    for (int j = 0; j < 16; ++j)
        *(float4*)(pb + (size_t)j * Hc) = acc[j];
}

// ---------------- K3: h2T[l][n][b] = lrelu(sum_k lrelu(sum_c part + b1) * W2 + b2) ----------------
// fp32 tiled GEMM: M=128 (batch half), N=128, K=128 in 8 steps of 16. 8x8 reg
// tile/thread. A-stage sums the <=7 chunk partials + bias, applies lrelu, and
// transposes into padded LDS.
__global__ __launch_bounds__(256) void k_h2(const float* __restrict__ part,
                                            const float* __restrict__ W2,
                                            const float* __restrict__ b1,
                                            const float* __restrict__ b2,
                                            float* __restrict__ h2T) {
    const int l = blockIdx.x >> 1;
    const int bbase = (blockIdx.x & 1) * 128;
    const int t = threadIdx.x;
    const int tx = t & 15, ty = t >> 4;
    __shared__ float As[16][132];
    __shared__ float Bs[16][Hc];
    __shared__ float Ts[32][Hc];
    float acc[8][8];
#pragma unroll
    for (int i = 0; i < 8; ++i)
#pragma unroll
        for (int j = 0; j < 8; ++j) acc[i][j] = 0.f;
    const int skk = t >> 4, sms = (t & 15) * 8;
    const int au = t >> 2, av4 = (t & 3) * 4;   // A-stage: m=au(+64), k-quad av4
    const int nch = l / CH + 1;
    const float* pl = part + (size_t)(l * NCH) * (Bc * Hc);
    const float* W2l = W2 + (size_t)l * Hc * Hc;
    for (int ks = 0; ks < 8; ++ks) {
        const int kcol = ks * 16 + av4;
        float4 a0 = {0.f, 0.f, 0.f, 0.f}, a1 = {0.f, 0.f, 0.f, 0.f};
        for (int cc = 0; cc < nch; ++cc) {
            const float* pc = pl + (size_t)cc * (Bc * Hc);
            const float4 q0 = *(const float4*)(pc + (size_t)(bbase + au) * Hc + kcol);
            const float4 q1 = *(const float4*)(pc + (size_t)(bbase + au + 64) * Hc + kcol);
            a0.x += q0.x; a0.y += q0.y; a0.z += q0.z; a0.w += q0.w;
            a1.x += q1.x; a1.y += q1.y; a1.z += q1.z; a1.w += q1.w;
        }
        const float4 bb = *(const float4*)(b1 + l * Hc + kcol);
        a0.x += bb.x; a0.y += bb.y; a0.z += bb.z; a0.w += bb.w;
        a1.x += bb.x; a1.y += bb.y; a1.z += bb.z; a1.w += bb.w;
        a0.x = (a0.x >= 0.f) ? a0.x : 0.1f * a0.x;
        a0.y = (a0.y >= 0.f) ? a0.y : 0.1f * a0.y;
        a0.z = (a0.z >= 0.f) ? a0.z : 0.1f * a0.z;
        a0.w = (a0.w >= 0.f) ? a0.w : 0.1f * a0.w;
        a1.x = (a1.x >= 0.f) ? a1.x : 0.1f * a1.x;
        a1.y = (a1.y >= 0.f) ? a1.y : 0.1f * a1.y;
        a1.z = (a1.z >= 0.f) ? a1.z : 0.1f * a1.z;
        a1.w = (a1.w >= 0.f) ? a1.w : 0.1f * a1.w;
        const int kb = ks * 16 + skk;
        *(float4*)&Bs[skk][sms]     = *(const float4*)(W2l + (size_t)kb * Hc + sms);
        *(float4*)&Bs[skk][sms + 4] = *(const float4*)(W2l + (size_t)kb * Hc + sms + 4);
        As[av4 + 0][au] = a0.x; As[av4 + 1][au] = a0.y;
        As[av4 + 2][au] = a0.z; As[av4 + 3][au] = a0.w;
        As[av4 + 0][au + 64] = a1.x; As[av4 + 1][au + 64] = a1.y;
        As[av4 + 2][au + 64] = a1.z; As[av4 + 3][au + 64] = a1.w;
        __syncthreads();
#pragma unroll
        for (int k = 0; k < 16; ++k) {
            float avr[8], bvr[8];
            *(float4*)&avr[0] = *(const float4*)&As[k][ty * 8];
            *(float4*)&avr[4] = *(const float4*)&As[k][ty * 8 + 4];
            *(float4*)&bvr[0] = *(const float4*)&Bs[k][tx * 8];
            *(float4*)&bvr[4] = *(const float4*)&Bs[k][tx * 8 + 4];
#pragma unroll
            for (int i = 0; i < 8; ++i)
#pragma unroll
                for (int j = 0; j < 8; ++j) acc[i][j] += avr[i] * bvr[j];
        }
        __syncthreads();
    }
    float bz[8];
    *(float4*)&bz[0] = *(const float4*)(b2 + l * Hc + tx * 8);
    *(float4*)&bz[4] = *(const float4*)(b2 + l * Hc + tx * 8 + 4);
    float res[8][8];
#pragma unroll
    for (int i = 0; i < 8; ++i)
#pragma unroll
        for (int j = 0; j < 8; ++j) {
            float v = acc[i][j] + bz[j];
            res[i][j] = (v >= 0.f) ? v : 0.1f * v;
        }
    // transpose-store via LDS in 4 chunks of 32 n-rows: h2T[l][n][bbase+m]
    for (int c = 0; c < 4; ++c) {
        if ((tx >> 2) == c) {
#pragma unroll
            for (int i = 0; i < 8; ++i)
#pragma unroll
                for (int j = 0; j < 8; ++j) Ts[(tx & 3) * 8 + j][ty * 8 + i] = res[i][j];
        }
        __syncthreads();
        const int r = t >> 3, m2 = (t & 7) * 16;
        float* dst = h2T + ((size_t)l * Hc + c * 32 + r) * Bc + bbase + m2;
#pragma unroll
        for (int u = 0; u < 4; ++u) *(float4*)(dst + u * 4) = *(const float4*)&Ts[r][m2 + u * 4];
        __syncthreads();
    }
}

// ---------------- K4: out[b, l+1, q] += sum_k h2T[l][k][b] * Wout[l][k][q] + bout[l][q] ----------------
__global__ __launch_bounds__(128) void k_out(const float* __restrict__ h2T,
                                             const float* __restrict__ Wout,
                                             const float* __restrict__ bout,
                                             float* __restrict__ out) {
    const int l = blockIdx.x >> 1;
    const int bh = blockIdx.x & 1;
    const int t = threadIdx.x;  // 0..127
    __shared__ float wl[Hc * Qc];
    __shared__ float bl[Qc];
    const float* wsrc = Wout + (size_t)l * Hc * Qc;
    for (int i = t; i < Hc * Qc; i += 128) wl[i] = wsrc[i];
    if (t < Qc) bl[t] = bout[l * Qc + t];
    __syncthreads();
    const int b = bh * 128 + t;
    float acc[Qc];
#pragma unroll
    for (int q = 0; q < Qc; ++q) acc[q] = bl[q];
    const float* h2l = h2T + (size_t)l * Hc * Bc + b;
    for (int k = 0; k < Hc; ++k) {
        const float av = h2l[(size_t)k * Bc];
        const float* wr = &wl[k * Qc];
#pragma unroll
        for (int q = 0; q < Qc; ++q) acc[q] += av * wr[q];
    }
    float* op = out + ((size_t)b * Lc + (l + 1)) * Qc;
#pragma unroll
    for (int q = 0; q < Qc; ++q) op[q] += acc[q];
}

extern "C" void kernel_launch(void* const* d_in, const int* in_sizes, int n_in,
                              void* d_out, int out_size, void* d_ws, size_t ws_size,
                              hipStream_t stream) {
    const float* x    = (const float*)d_in[0];
    const float* bias = (const float*)d_in[1];
    const float* DW   = (const float*)d_in[2];
    const float* w0   = (const float*)d_in[3];
    const float* b0   = (const float*)d_in[4];
    const float* W1   = (const float*)d_in[5];
    const float* b1   = (const float*)d_in[6];
    const float* W2   = (const float*)d_in[7];
    const float* b2   = (const float*)d_in[8];
    const float* Wout = (const float*)d_in[9];
    const float* bout = (const float*)d_in[10];
    float* out = (float*)d_out;

    int*   idxT = (int*)d_ws;
    float* part = (float*)((char*)d_ws + 204800);
    float* h2T  = (float*)((char*)d_ws + 204800 + 182583296);

    k_idx<<<Lc, 256, 0, stream>>>(x, idxT);
    k_dca<<<Bc * 5, 256, 0, stream>>>(DW, bias, w0, b0, idxT, out);
    k_h1<<<LM1c * NCH, 512, 0, stream>>>(W1, idxT, part);
    k_h2<<<LM1c * 2, 256, 0, stream>>>(part, W2, b1, b2, h2T);
    k_out<<<LM1c * 2, 128, 0, stream>>>(h2T, Wout, bout, out);
}

// Round 10
// 190.163 us; speedup vs baseline: 2.0318x; 2.0318x over previous
//
#include <hip/hip_runtime.h>

// arHOCA: L=200 positions, Q=21 alphabet, H=128 hidden, B=256 batch.
// x is one-hot => all "x @ W" contractions are gather-sums over idx[b,l].
//
// DCA mask (faithful to reference): mask loop is `for i in range(Q)`, so only
// row-blocks 1..20 / col-blocks 0..19 are active; mask[d,c]=1 iff blk(c)<blk(d).
// => out_dca[b,j] = sum_{l=j/Q+1}^{20} DW[l*Q+idx[b,l], j].
//
// k_h1 is a chunked LDS-broadcast streamer: block = (l, 32-wide lp-chunk);
// each W1 byte is read from HBM exactly once (chunks are disjoint); per-lp the
// 21 candidate rows (10.5 KB) sit in LDS and are broadcast to all 256 batches.
// Partial sums (per chunk) go to ws; k_h2 sums partials + bias + lrelu.
// 1024 threads/block, 8 batches/thread => acc is 32 VGPRs: NO SPILL (R9 bug).
//
// ws layout: idxT [200][256] int (204800 B)
//            | part [199][7][256][128] f32 (182583296 B)
//            | h2T [199][128][256] f32 (26083328 B)   => ~209 MB.

#define Lc   200
#define Qc   21
#define Hc   128
#define Bc   256
#define LQc  4200
#define LM1c 199
#define CH   32    // lp chunk size
#define NCH  7     // max chunks per l

// ---------------- K0: idxT[l][b] = argmax_c x[b,l,c] ----------------
__global__ __launch_bounds__(256) void k_idx(const float* __restrict__ x,
                                             int* __restrict__ idxT) {
    const int l = blockIdx.x;       // 0..199
    const int b = threadIdx.x;      // 0..255
    const float* p = x + ((size_t)b * Lc + l) * Qc;
    int id = 0;
#pragma unroll
    for (int c = 0; c < Qc; ++c) id = (p[c] > 0.5f) ? c : id;
    idxT[l * Bc + b] = id;          // coalesced store
}

// ---------------- K1: DCA gather + bias + out0 (w0+b0) ----------------
// out[b, j] = bias[j] + sum_{l = j/Q+1 .. 20} DW[l*Q+idx[b,l], j]  (+ w0+b0 for j<Q)
__global__ __launch_bounds__(256) void k_dca(const float* __restrict__ DW,
                                             const float* __restrict__ bias,
                                             const float* __restrict__ w0,
                                             const float* __restrict__ b0,
                                             const int* __restrict__ idxT,
                                             float* __restrict__ out) {
    const int b = blockIdx.x / 5, chunk = blockIdx.x % 5;
    const int j0 = chunk * 1024 + threadIdx.x * 4;
    if (j0 >= LQc) return;
    float a[4];
    const float4 bv = *(const float4*)(bias + j0);
    a[0] = bv.x; a[1] = bv.y; a[2] = bv.z; a[3] = bv.w;
    if (j0 < Qc) {
#pragma unroll
        for (int e = 0; e < 4; ++e) {
            int j = j0 + e;
            if (j < Qc) a[e] += w0[j] + b0[j];
        }
    }
    if (j0 < (Qc - 1) * Qc) {
        const int lmin = j0 / Qc + 1;
        for (int l = lmin; l < Qc; ++l) {
            const int iv = idxT[l * Bc + b];
            const float4 v = *(const float4*)(DW + (size_t)(l * Qc + iv) * LQc + j0);
            const int thr = l * Qc;  // contribute iff j < l*Q
            a[0] += (j0     < thr) ? v.x : 0.f;
            a[1] += (j0 + 1 < thr) ? v.y : 0.f;
            a[2] += (j0 + 2 < thr) ? v.z : 0.f;
            a[3] += (j0 + 3 < thr) ? v.w : 0.f;
        }
    }
    float4 o = {a[0], a[1], a[2], a[3]};
    *(float4*)(out + (size_t)b * LQc + j0) = o;
}

// ---------------- K2: chunked LDS-broadcast partial sums ----------------
// part[l][c][b][h] = sum_{lp in chunk c, lp<=l} W1[l, lp*Q+idx[b,lp], h]
// Block = (l, chunk), 1024 threads (16 waves). Thread = (hq = h-quad 0..31,
// bg = batch-group 0..31 of 8 batches). Per lp: the 21-row tile (10.5 KB) is
// staged once (reg-staged, double-buffered, ONE barrier/iter) and
// broadcast-read from LDS. Each W1 element: exactly one HBM fetch kernel-wide.
// Per-thread state: acc 32 VGPR + 1 staging float4 -> no spill.
__global__ __launch_bounds__(1024, 2) void k_h1(const float* __restrict__ W1,
                                                const int* __restrict__ idxT,
                                                float* __restrict__ part) {
    const int bid = blockIdx.x;            // 0..1392
    const int l = bid / NCH, c = bid % NCH;
    const int lo = c * CH;
    if (lo > l) return;                    // invalid chunk for this l
    const int hi = (l < lo + CH - 1) ? l : lo + CH - 1;
    const int n = hi - lo + 1;             // 1..32 iterations

    const int t = threadIdx.x;
    const int hq = t & 31;                 // h-quad: h = hq*4 .. hq*4+3
    const int bg = t >> 5;                 // batch group: b = bg*8 .. bg*8+7

    __shared__ __align__(16) float tile[2][Qc * 132];  // padded rows (132 floats)
    __shared__ int idxs[CH * Bc];

    // stage all chunk idx rows (n*256 ints = n*64 int4), coalesced
    {
        const int4* isrc = (const int4*)(idxT + lo * Bc);
        int4* idst = (int4*)idxs;
        for (int i = t; i < n * 64; i += 1024) idst[i] = isrc[i];
    }

    // stage tile 0 (2688 floats = 672 float4): i -> row i>>5, col (i&31)*4
    const float* Wsrc = W1 + (size_t)l * (LQc * Hc) + (size_t)lo * (Qc * Hc);
    if (t < 672) {
        const float4 q = ((const float4*)Wsrc)[t];
        *(float4*)&tile[0][(t >> 5) * 132 + (t & 31) * 4] = q;
    }
    __syncthreads();

    float4 acc[8];
#pragma unroll
    for (int j = 0; j < 8; ++j) acc[j] = (float4){0.f, 0.f, 0.f, 0.f};

    int cur = 0;
    for (int k = 0; k < n; ++k) {
        // async stage-ahead: issue global load for tile k+1 (1 float4/thread)
        float4 p;
        const bool st = (k + 1 < n) && (t < 672);
        if (st) p = ((const float4*)(Wsrc + (size_t)(k + 1) * (Qc * Hc)))[t];
        // broadcast-accumulate tile k (HBM latency of p hides under this)
        const float* tb = &tile[cur][hq * 4];
        const int* ib = &idxs[k * Bc + bg * 8];
#pragma unroll
        for (int j = 0; j < 8; ++j) {
            const float4 v = *(const float4*)(tb + ib[j] * 132);
            acc[j].x += v.x; acc[j].y += v.y; acc[j].z += v.z; acc[j].w += v.w;
        }
        // write tile k+1 into the other buffer (its readers finished before
        // the previous barrier), then ONE barrier
        if (st) *(float4*)&tile[cur ^ 1][(t >> 5) * 132 + (t & 31) * 4] = p;
        __syncthreads();
        cur ^= 1;
    }

    // store partials: part[(l*7+c)][b][h]; lanes 0..31 share bg -> 512B bursts
    float* pb = part + ((size_t)(l * NCH + c) * Bc + bg * 8) * Hc + hq * 4;
#pragma unroll
    for (int j = 0; j < 8; ++j)
        *(float4*)(pb + (size_t)j * Hc) = acc[j];
}

// ---------------- K3: h2T[l][n][b] = lrelu(sum_k lrelu(sum_c part + b1) * W2 + b2) ----------------
// fp32 tiled GEMM: M=128 (batch half), N=128, K=128 in 8 steps of 16. 8x8 reg
// tile/thread. A-stage sums the <=7 chunk partials + bias, applies lrelu, and
// transposes into padded LDS.
__global__ __launch_bounds__(256) void k_h2(const float* __restrict__ part,
                                            const float* __restrict__ W2,
                                            const float* __restrict__ b1,
                                            const float* __restrict__ b2,
                                            float* __restrict__ h2T) {
    const int l = blockIdx.x >> 1;
    const int bbase = (blockIdx.x & 1) * 128;
    const int t = threadIdx.x;
    const int tx = t & 15, ty = t >> 4;
    __shared__ float As[16][132];
    __shared__ float Bs[16][Hc];
    __shared__ float Ts[32][Hc];
    float acc[8][8];
#pragma unroll
    for (int i = 0; i < 8; ++i)
#pragma unroll
        for (int j = 0; j < 8; ++j) acc[i][j] = 0.f;
    const int skk = t >> 4, sms = (t & 15) * 8;
    const int au = t >> 2, av4 = (t & 3) * 4;   // A-stage: m=au(+64), k-quad av4
    const int nch = l / CH + 1;
    const float* pl = part + (size_t)(l * NCH) * (Bc * Hc);
    const float* W2l = W2 + (size_t)l * Hc * Hc;
    for (int ks = 0; ks < 8; ++ks) {
        const int kcol = ks * 16 + av4;
        float4 a0 = {0.f, 0.f, 0.f, 0.f}, a1 = {0.f, 0.f, 0.f, 0.f};
        for (int cc = 0; cc < nch; ++cc) {
            const float* pc = pl + (size_t)cc * (Bc * Hc);
            const float4 q0 = *(const float4*)(pc + (size_t)(bbase + au) * Hc + kcol);
            const float4 q1 = *(const float4*)(pc + (size_t)(bbase + au + 64) * Hc + kcol);
            a0.x += q0.x; a0.y += q0.y; a0.z += q0.z; a0.w += q0.w;
            a1.x += q1.x; a1.y += q1.y; a1.z += q1.z; a1.w += q1.w;
        }
        const float4 bb = *(const float4*)(b1 + l * Hc + kcol);
        a0.x += bb.x; a0.y += bb.y; a0.z += bb.z; a0.w += bb.w;
        a1.x += bb.x; a1.y += bb.y; a1.z += bb.z; a1.w += bb.w;
        a0.x = (a0.x >= 0.f) ? a0.x : 0.1f * a0.x;
        a0.y = (a0.y >= 0.f) ? a0.y : 0.1f * a0.y;
        a0.z = (a0.z >= 0.f) ? a0.z : 0.1f * a0.z;
        a0.w = (a0.w >= 0.f) ? a0.w : 0.1f * a0.w;
        a1.x = (a1.x >= 0.f) ? a1.x : 0.1f * a1.x;
        a1.y = (a1.y >= 0.f) ? a1.y : 0.1f * a1.y;
        a1.z = (a1.z >= 0.f) ? a1.z : 0.1f * a1.z;
        a1.w = (a1.w >= 0.f) ? a1.w : 0.1f * a1.w;
        const int kb = ks * 16 + skk;
        *(float4*)&Bs[skk][sms]     = *(const float4*)(W2l + (size_t)kb * Hc + sms);
        *(float4*)&Bs[skk][sms + 4] = *(const float4*)(W2l + (size_t)kb * Hc + sms + 4);
        As[av4 + 0][au] = a0.x; As[av4 + 1][au] = a0.y;
        As[av4 + 2][au] = a0.z; As[av4 + 3][au] = a0.w;
        As[av4 + 0][au + 64] = a1.x; As[av4 + 1][au + 64] = a1.y;
        As[av4 + 2][au + 64] = a1.z; As[av4 + 3][au + 64] = a1.w;
        __syncthreads();
#pragma unroll
        for (int k = 0; k < 16; ++k) {
            float avr[8], bvr[8];
            *(float4*)&avr[0] = *(const float4*)&As[k][ty * 8];
            *(float4*)&avr[4] = *(const float4*)&As[k][ty * 8 + 4];
            *(float4*)&bvr[0] = *(const float4*)&Bs[k][tx * 8];
            *(float4*)&bvr[4] = *(const float4*)&Bs[k][tx * 8 + 4];
#pragma unroll
            for (int i = 0; i < 8; ++i)
#pragma unroll
                for (int j = 0; j < 8; ++j) acc[i][j] += avr[i] * bvr[j];
        }
        __syncthreads();
    }
    float bz[8];
    *(float4*)&bz[0] = *(const float4*)(b2 + l * Hc + tx * 8);
    *(float4*)&bz[4] = *(const float4*)(b2 + l * Hc + tx * 8 + 4);
    float res[8][8];
#pragma unroll
    for (int i = 0; i < 8; ++i)
#pragma unroll
        for (int j = 0; j < 8; ++j) {
            float v = acc[i][j] + bz[j];
            res[i][j] = (v >= 0.f) ? v : 0.1f * v;
        }
    // transpose-store via LDS in 4 chunks of 32 n-rows: h2T[l][n][bbase+m]
    for (int c = 0; c < 4; ++c) {
        if ((tx >> 2) == c) {
#pragma unroll
            for (int i = 0; i < 8; ++i)
#pragma unroll
                for (int j = 0; j < 8; ++j) Ts[(tx & 3) * 8 + j][ty * 8 + i] = res[i][j];
        }
        __syncthreads();
        const int r = t >> 3, m2 = (t & 7) * 16;
        float* dst = h2T + ((size_t)l * Hc + c * 32 + r) * Bc + bbase + m2;
#pragma unroll
        for (int u = 0; u < 4; ++u) *(float4*)(dst + u * 4) = *(const float4*)&Ts[r][m2 + u * 4];
        __syncthreads();
    }
}

// ---------------- K4: out[b, l+1, q] += sum_k h2T[l][k][b] * Wout[l][k][q] + bout[l][q] ----------------
__global__ __launch_bounds__(128) void k_out(const float* __restrict__ h2T,
                                             const float* __restrict__ Wout,
                                             const float* __restrict__ bout,
                                             float* __restrict__ out) {
    const int l = blockIdx.x >> 1;
    const int bh = blockIdx.x & 1;
    const int t = threadIdx.x;  // 0..127
    __shared__ float wl[Hc * Qc];
    __shared__ float bl[Qc];
    const float* wsrc = Wout + (size_t)l * Hc * Qc;
    for (int i = t; i < Hc * Qc; i += 128) wl[i] = wsrc[i];
    if (t < Qc) bl[t] = bout[l * Qc + t];
    __syncthreads();
    const int b = bh * 128 + t;
    float acc[Qc];
#pragma unroll
    for (int q = 0; q < Qc; ++q) acc[q] = bl[q];
    const float* h2l = h2T + (size_t)l * Hc * Bc + b;
    for (int k = 0; k < Hc; ++k) {
        const float av = h2l[(size_t)k * Bc];
        const float* wr = &wl[k * Qc];
#pragma unroll
        for (int q = 0; q < Qc; ++q) acc[q] += av * wr[q];
    }
    float* op = out + ((size_t)b * Lc + (l + 1)) * Qc;
#pragma unroll
    for (int q = 0; q < Qc; ++q) op[q] += acc[q];
}

extern "C" void kernel_launch(void* const* d_in, const int* in_sizes, int n_in,
                              void* d_out, int out_size, void* d_ws, size_t ws_size,
                              hipStream_t stream) {
    const float* x    = (const float*)d_in[0];
    const float* bias = (const float*)d_in[1];
    const float* DW   = (const float*)d_in[2];
    const float* w0   = (const float*)d_in[3];
    const float* b0   = (const float*)d_in[4];
    const float* W1   = (const float*)d_in[5];
    const float* b1   = (const float*)d_in[6];
    const float* W2   = (const float*)d_in[7];
    const float* b2   = (const float*)d_in[8];
    const float* Wout = (const float*)d_in[9];
    const float* bout = (const float*)d_in[10];
    float* out = (float*)d_out;

    int*   idxT = (int*)d_ws;
    float* part = (float*)((char*)d_ws + 204800);
    float* h2T  = (float*)((char*)d_ws + 204800 + 182583296);

    k_idx<<<Lc, 256, 0, stream>>>(x, idxT);
    k_dca<<<Bc * 5, 256, 0, stream>>>(DW, bias, w0, b0, idxT, out);
    k_h1<<<LM1c * NCH, 1024, 0, stream>>>(W1, idxT, part);
    k_h2<<<LM1c * 2, 256, 0, stream>>>(part, W2, b1, b2, h2T);
    k_out<<<LM1c * 2, 128, 0, stream>>>(h2T, Wout, bout, out);
}

// Round 11
// 172.062 us; speedup vs baseline: 2.2456x; 1.1052x over previous
//
#include <hip/hip_runtime.h>

// arHOCA: L=200 positions, Q=21 alphabet, H=128 hidden, B=256 batch.
// x is one-hot => all "x @ W" contractions are gather-sums over idx[b,l].
//
// DCA mask (faithful to reference): mask loop is `for i in range(Q)`, so only
// row-blocks 1..20 / col-blocks 0..19 are active; mask[d,c]=1 iff blk(c)<blk(d).
// => out_dca[b,j] = sum_{l=j/Q+1}^{20} DW[l*Q+idx[b,l], j].
//
// k_h1: chunked LDS-broadcast streamer: block = (l, 48-wide lp-chunk); each W1
// byte is read from HBM exactly once; per-lp the 21 candidate rows (10.5 KB)
// are broadcast from LDS to all 256 batches. Partials go to ws.
// k_h2: sums partials + b1 + lrelu (A-stage), 128x128x128 fp32 GEMM + b2 +
// lrelu, then FUSED Wout contraction accumulating directly into out (h2 never
// touches HBM).
//
// ws layout: idxT [200][256] int (204800 B)
//            | part [199][5][256][128] f32 (130416640 B)   => ~130.6 MB.

#define Lc   200
#define Qc   21
#define Hc   128
#define Bc   256
#define LQc  4200
#define LM1c 199
#define CH   48    // lp chunk size
#define NCH  5     // max chunks per l

// ---------------- K0: idxT[l][b] = argmax_c x[b,l,c] ----------------
__global__ __launch_bounds__(256) void k_idx(const float* __restrict__ x,
                                             int* __restrict__ idxT) {
    const int l = blockIdx.x;       // 0..199
    const int b = threadIdx.x;      // 0..255
    const float* p = x + ((size_t)b * Lc + l) * Qc;
    int id = 0;
#pragma unroll
    for (int c = 0; c < Qc; ++c) id = (p[c] > 0.5f) ? c : id;
    idxT[l * Bc + b] = id;          // coalesced store
}

// ---------------- K1: DCA gather + bias + out0 (w0+b0) ----------------
// out[b, j] = bias[j] + sum_{l = j/Q+1 .. 20} DW[l*Q+idx[b,l], j]  (+ w0+b0 for j<Q)
__global__ __launch_bounds__(256) void k_dca(const float* __restrict__ DW,
                                             const float* __restrict__ bias,
                                             const float* __restrict__ w0,
                                             const float* __restrict__ b0,
                                             const int* __restrict__ idxT,
                                             float* __restrict__ out) {
    const int b = blockIdx.x / 5, chunk = blockIdx.x % 5;
    const int j0 = chunk * 1024 + threadIdx.x * 4;
    if (j0 >= LQc) return;
    float a[4];
    const float4 bv = *(const float4*)(bias + j0);
    a[0] = bv.x; a[1] = bv.y; a[2] = bv.z; a[3] = bv.w;
    if (j0 < Qc) {
#pragma unroll
        for (int e = 0; e < 4; ++e) {
            int j = j0 + e;
            if (j < Qc) a[e] += w0[j] + b0[j];
        }
    }
    if (j0 < (Qc - 1) * Qc) {
        const int lmin = j0 / Qc + 1;
        for (int l = lmin; l < Qc; ++l) {
            const int iv = idxT[l * Bc + b];
            const float4 v = *(const float4*)(DW + (size_t)(l * Qc + iv) * LQc + j0);
            const int thr = l * Qc;  // contribute iff j < l*Q
            a[0] += (j0     < thr) ? v.x : 0.f;
            a[1] += (j0 + 1 < thr) ? v.y : 0.f;
            a[2] += (j0 + 2 < thr) ? v.z : 0.f;
            a[3] += (j0 + 3 < thr) ? v.w : 0.f;
        }
    }
    float4 o = {a[0], a[1], a[2], a[3]};
    *(float4*)(out + (size_t)b * LQc + j0) = o;
}

// ---------------- K2: chunked LDS-broadcast partial sums ----------------
// part[l][c][b][h] = sum_{lp in chunk c, lp<=l} W1[l, lp*Q+idx[b,lp], h]
// Block = (l, chunk), 1024 threads (16 waves). Thread = (hq 0..31, bg 0..31 of
// 8 batches). Per lp: 21-row tile staged once (reg-staged, double-buffered,
// ONE barrier/iter), broadcast-read from LDS. acc = 32 VGPR: no spill.
// l descending so the longest chains start first.
__global__ __launch_bounds__(1024, 2) void k_h1(const float* __restrict__ W1,
                                                const int* __restrict__ idxT,
                                                float* __restrict__ part) {
    const int bid = blockIdx.x;            // 0..994
    const int l = 198 - bid / NCH, c = bid % NCH;
    const int lo = c * CH;
    if (lo > l) return;                    // invalid chunk for this l
    const int hi = (l < lo + CH - 1) ? l : lo + CH - 1;
    const int n = hi - lo + 1;             // 1..48 iterations

    const int t = threadIdx.x;
    const int hq = t & 31;                 // h-quad: h = hq*4 .. hq*4+3
    const int bg = t >> 5;                 // batch group: b = bg*8 .. bg*8+7

    __shared__ __align__(16) float tile[2][Qc * 132];  // padded rows (132 floats)
    __shared__ int idxs[CH * Bc];

    // stage all chunk idx rows (n*256 ints = n*64 int4), coalesced
    {
        const int4* isrc = (const int4*)(idxT + lo * Bc);
        int4* idst = (int4*)idxs;
        for (int i = t; i < n * 64; i += 1024) idst[i] = isrc[i];
    }

    // stage tile 0 (2688 floats = 672 float4): i -> row i>>5, col (i&31)*4
    const float* Wsrc = W1 + (size_t)l * (LQc * Hc) + (size_t)lo * (Qc * Hc);
    if (t < 672) {
        const float4 q = ((const float4*)Wsrc)[t];
        *(float4*)&tile[0][(t >> 5) * 132 + (t & 31) * 4] = q;
    }
    __syncthreads();

    float4 acc[8];
#pragma unroll
    for (int j = 0; j < 8; ++j) acc[j] = (float4){0.f, 0.f, 0.f, 0.f};

    int cur = 0;
    for (int k = 0; k < n; ++k) {
        // async stage-ahead: issue global load for tile k+1 (1 float4/thread)
        float4 p;
        const bool st = (k + 1 < n) && (t < 672);
        if (st) p = ((const float4*)(Wsrc + (size_t)(k + 1) * (Qc * Hc)))[t];
        // broadcast-accumulate tile k (HBM latency of p hides under this)
        const float* tb = &tile[cur][hq * 4];
        const int* ib = &idxs[k * Bc + bg * 8];
#pragma unroll
        for (int j = 0; j < 8; ++j) {
            const float4 v = *(const float4*)(tb + ib[j] * 132);
            acc[j].x += v.x; acc[j].y += v.y; acc[j].z += v.z; acc[j].w += v.w;
        }
        // write tile k+1 into the other buffer, then ONE barrier
        if (st) *(float4*)&tile[cur ^ 1][(t >> 5) * 132 + (t & 31) * 4] = p;
        __syncthreads();
        cur ^= 1;
    }

    // store partials: part[(l*5+c)][b][h]; lanes 0..31 share bg -> 512B bursts
    float* pb = part + ((size_t)(l * NCH + c) * Bc + bg * 8) * Hc + hq * 4;
#pragma unroll
    for (int j = 0; j < 8; ++j)
        *(float4*)(pb + (size_t)j * Hc) = acc[j];
}

// ---------------- K3 (fused): h2 GEMM + Wout contraction -> out ----------------
// A-stage: h1[b][k] = lrelu(sum_c part[l][c][b][k] + b1[l][k]) transposed into
// LDS. GEMM: h2 = lrelu(h1 @ W2 + b2) in regs. Epilogue: out[b,l+1,q] +=
// sum_n h2[b][n]*Wout[l][n][q] + bout[l][q], via Ts transpose + wl in LDS.
__global__ __launch_bounds__(256) void k_h2(const float* __restrict__ part,
                                            const float* __restrict__ W2,
                                            const float* __restrict__ b1,
                                            const float* __restrict__ b2,
                                            const float* __restrict__ Wout,
                                            const float* __restrict__ bout,
                                            float* __restrict__ out) {
    const int l = blockIdx.x >> 1;
    const int bbase = (blockIdx.x & 1) * 128;
    const int t = threadIdx.x;
    const int tx = t & 15, ty = t >> 4;
    __shared__ float As[16][132];
    __shared__ float Bs[16][Hc];
    __shared__ float Ts[32][Hc];
    __shared__ float wl[Hc][22];           // Wout[l] padded; col 21 = 0
    float acc[8][8];
#pragma unroll
    for (int i = 0; i < 8; ++i)
#pragma unroll
        for (int j = 0; j < 8; ++j) acc[i][j] = 0.f;
    // stage Wout[l] (128x21) + zero pad col
    {
        const float* wsrc = Wout + (size_t)l * Hc * Qc;
        for (int i = t; i < Hc * Qc; i += 256) wl[i / Qc][i % Qc] = wsrc[i];
        if (t < Hc) wl[t][21] = 0.f;
    }
    const int skk = t >> 4, sms = (t & 15) * 8;
    const int au = t >> 2, av4 = (t & 3) * 4;   // A-stage: m=au(+64), k-quad av4
    const int nch = l / CH + 1;
    const float* pl = part + (size_t)(l * NCH) * (Bc * Hc);
    const float* W2l = W2 + (size_t)l * Hc * Hc;
    for (int ks = 0; ks < 8; ++ks) {
        const int kcol = ks * 16 + av4;
        float4 a0 = {0.f, 0.f, 0.f, 0.f}, a1 = {0.f, 0.f, 0.f, 0.f};
        for (int cc = 0; cc < nch; ++cc) {
            const float* pc = pl + (size_t)cc * (Bc * Hc);
            const float4 q0 = *(const float4*)(pc + (size_t)(bbase + au) * Hc + kcol);
            const float4 q1 = *(const float4*)(pc + (size_t)(bbase + au + 64) * Hc + kcol);
            a0.x += q0.x; a0.y += q0.y; a0.z += q0.z; a0.w += q0.w;
            a1.x += q1.x; a1.y += q1.y; a1.z += q1.z; a1.w += q1.w;
        }
        const float4 bb = *(const float4*)(b1 + l * Hc + kcol);
        a0.x += bb.x; a0.y += bb.y; a0.z += bb.z; a0.w += bb.w;
        a1.x += bb.x; a1.y += bb.y; a1.z += bb.z; a1.w += bb.w;
        a0.x = (a0.x >= 0.f) ? a0.x : 0.1f * a0.x;
        a0.y = (a0.y >= 0.f) ? a0.y : 0.1f * a0.y;
        a0.z = (a0.z >= 0.f) ? a0.z : 0.1f * a0.z;
        a0.w = (a0.w >= 0.f) ? a0.w : 0.1f * a0.w;
        a1.x = (a1.x >= 0.f) ? a1.x : 0.1f * a1.x;
        a1.y = (a1.y >= 0.f) ? a1.y : 0.1f * a1.y;
        a1.z = (a1.z >= 0.f) ? a1.z : 0.1f * a1.z;
        a1.w = (a1.w >= 0.f) ? a1.w : 0.1f * a1.w;
        const int kb = ks * 16 + skk;
        *(float4*)&Bs[skk][sms]     = *(const float4*)(W2l + (size_t)kb * Hc + sms);
        *(float4*)&Bs[skk][sms + 4] = *(const float4*)(W2l + (size_t)kb * Hc + sms + 4);
        As[av4 + 0][au] = a0.x; As[av4 + 1][au] = a0.y;
        As[av4 + 2][au] = a0.z; As[av4 + 3][au] = a0.w;
        As[av4 + 0][au + 64] = a1.x; As[av4 + 1][au + 64] = a1.y;
        As[av4 + 2][au + 64] = a1.z; As[av4 + 3][au + 64] = a1.w;
        __syncthreads();
#pragma unroll
        for (int k = 0; k < 16; ++k) {
            float avr[8], bvr[8];
            *(float4*)&avr[0] = *(const float4*)&As[k][ty * 8];
            *(float4*)&avr[4] = *(const float4*)&As[k][ty * 8 + 4];
            *(float4*)&bvr[0] = *(const float4*)&Bs[k][tx * 8];
            *(float4*)&bvr[4] = *(const float4*)&Bs[k][tx * 8 + 4];
#pragma unroll
            for (int i = 0; i < 8; ++i)
#pragma unroll
                for (int j = 0; j < 8; ++j) acc[i][j] += avr[i] * bvr[j];
        }
        __syncthreads();
    }
    float bz[8];
    *(float4*)&bz[0] = *(const float4*)(b2 + l * Hc + tx * 8);
    *(float4*)&bz[4] = *(const float4*)(b2 + l * Hc + tx * 8 + 4);
    float res[8][8];
#pragma unroll
    for (int i = 0; i < 8; ++i)
#pragma unroll
        for (int j = 0; j < 8; ++j) {
            float v = acc[i][j] + bz[j];
            res[i][j] = (v >= 0.f) ? v : 0.1f * v;
        }
    // Epilogue: out[b, l+1, q] += sum_n res_T[n][m] * wl[n][q] + bout.
    // Thread owns (m = t&127, q-half = t>>7): racc statically indexed (11 regs).
    const int m = t & 127, qh = t >> 7;
    const int q0 = qh * 11;                // 0..10 / 11..21(pad)
    float racc[11];
#pragma unroll
    for (int qi = 0; qi < 11; ++qi) racc[qi] = 0.f;
    for (int c = 0; c < 4; ++c) {
        if ((tx >> 2) == c) {
#pragma unroll
            for (int i = 0; i < 8; ++i)
#pragma unroll
                for (int j = 0; j < 8; ++j) Ts[(tx & 3) * 8 + j][ty * 8 + i] = res[i][j];
        }
        __syncthreads();
#pragma unroll 4
        for (int rr = 0; rr < 32; ++rr) {
            const float v = Ts[rr][m];     // banks: m across lanes, conflict-free
            const float* wr = &wl[c * 32 + rr][q0];  // wave-uniform: broadcast
#pragma unroll
            for (int qi = 0; qi < 11; ++qi) racc[qi] += v * wr[qi];
        }
        __syncthreads();
    }
    const int b = bbase + m;
    float* op = out + ((size_t)b * Lc + (l + 1)) * Qc;
    const float* bo = bout + l * Qc;
#pragma unroll
    for (int qi = 0; qi < 11; ++qi) {
        const int q = q0 + qi;
        if (q < Qc) op[q] += racc[qi] + bo[q];
    }
}

extern "C" void kernel_launch(void* const* d_in, const int* in_sizes, int n_in,
                              void* d_out, int out_size, void* d_ws, size_t ws_size,
                              hipStream_t stream) {
    const float* x    = (const float*)d_in[0];
    const float* bias = (const float*)d_in[1];
    const float* DW   = (const float*)d_in[2];
    const float* w0   = (const float*)d_in[3];
    const float* b0   = (const float*)d_in[4];
    const float* W1   = (const float*)d_in[5];
    const float* b1   = (const float*)d_in[6];
    const float* W2   = (const float*)d_in[7];
    const float* b2   = (const float*)d_in[8];
    const float* Wout = (const float*)d_in[9];
    const float* bout = (const float*)d_in[10];
    float* out = (float*)d_out;

    int*   idxT = (int*)d_ws;
    float* part = (float*)((char*)d_ws + 204800);

    k_idx<<<Lc, 256, 0, stream>>>(x, idxT);
    k_dca<<<Bc * 5, 256, 0, stream>>>(DW, bias, w0, b0, idxT, out);
    k_h1<<<LM1c * NCH, 1024, 0, stream>>>(W1, idxT, part);
    k_h2<<<LM1c * 2, 256, 0, stream>>>(part, W2, b1, b2, Wout, bout, out);
}